// Round 10
// baseline (267.595 us; speedup 1.0000x reference)
//
#include <hip/hip_runtime.h>

#define MBLK 32

typedef __attribute__((ext_vector_type(8))) short bf16x8;
typedef __attribute__((ext_vector_type(16))) float f32x16;

__device__ __forceinline__ unsigned short f2bf(float x){
  unsigned int u = __float_as_uint(x);
  u = u + 0x7FFFu + ((u >> 16) & 1u);
  return (unsigned short)(u >> 16);
}
__device__ __forceinline__ float bf2f(unsigned short s){
  return __uint_as_float(((unsigned int)s) << 16);
}
__device__ __forceinline__ float sigm(float x){
  return __builtin_amdgcn_rcpf(1.0f + __expf(-x));
}
__device__ __forceinline__ float tanh_(float x){
  return 1.0f - 2.0f*__builtin_amdgcn_rcpf(__expf(2.0f*x) + 1.0f);
}
// pack 2 f32 -> 2 bf16 (RNE), lo = first operand
__device__ __forceinline__ unsigned int pk_bf16(float lo, float hi){
  unsigned int r;
  asm("v_cvt_pk_bf16_f32 %0, %1, %2" : "=v"(r) : "v"(lo), "v"(hi));
  return r;
}

// 512-thread block, 8 waves, MBLK=32, 256 blocks = 1 block/CU,
// __launch_bounds__(512,2) -> <=256 VGPR, 2 waves/SIMD.
// Gate GEMM via mfma_f32_32x32x16_bf16, WEIGHTS on A(M)-side, ACTIVATIONS
// on B(N)-side: C col=lane&31 = sample; lane-local nonlin; h-write = 2
// contiguous ds_write_b64. (r8 structure, 175us dispatch, passed.)
// vs r8:
//  - persistent bias accumulators (prologue MFMA); per-step first MFMA
//    takes bias as C-in -> no 32 v_mov acc-init, no per-step bias MFMA.
//  - pre-barrier partial-disp: lanes compute 16-fma partials from the
//    post-mask Q bits (bit-exact vs LDS h) into pdL[32][17]; pred disp =
//    1 b64 read + 4 shfl (was b64 + 4 b128 + 8 bf2f + 16 fma + 4 shfl).
//    pwL LDS array deleted (per-lane pw regs).
//  - hoisted LDS row base pointers (imm-offset ds_reads).
__global__ __launch_bounds__(512, 2) void traj_kernel(
    const float* __restrict__ img, const float* __restrict__ obs_pos,
    const int* __restrict__ hist, const float* __restrict__ rel,
    const float* __restrict__ h0, const float* __restrict__ W_ih,
    const float* __restrict__ W_hh, const float* __restrict__ b_ih,
    const float* __restrict__ b_hh, const float* __restrict__ eW,
    const float* __restrict__ eb, const float* __restrict__ pW,
    const float* __restrict__ pb, float* __restrict__ out)
{
  __shared__ unsigned short xh[2][MBLK*200];
  __shared__ float relL[MBLK*40];
  __shared__ float imgcL[MBLK*2];
  __shared__ float2 pdL[32][17];      // disp partials, +1 pad (bank spread)

  const int tid   = threadIdx.x;
  const int wv    = tid >> 6;          // 0..7
  const int lane  = tid & 63;
  const int m     = lane & 31;         // sample owned by this lane (MFMA N-col)
  const int khalf = lane >> 5;         // K-half within a 16-K step
  const int hb    = khalf*4;           // hidden sub-offset
  const int g0    = blockIdx.x * MBLK;
  const int dm    = tid >> 4;          // sample 0..31 (16 threads/sample)
  const int i16   = tid & 15;

  // ---- cooperative staging ----
  for (int idx = tid; idx < MBLK*40; idx += 512) relL[idx] = rel[g0*40 + idx];

  // ---- img_embedding @ pred_W[:,128:].T  (once; constant over pred steps) ----
  {
    const float* row = img + (size_t)(g0 + dm)*2048 + i16*128;
    const float* p0  = pW + 128 + i16*128;
    const float* p1  = pW + 2176 + 128 + i16*128;
    float s0 = 0.f, s1 = 0.f;
    #pragma unroll
    for (int v = 0; v < 32; v++){
      float4 a  = ((const float4*)row)[v];
      float4 w0 = ((const float4*)p0)[v];
      float4 w1 = ((const float4*)p1)[v];
      s0 += a.x*w0.x + a.y*w0.y + a.z*w0.z + a.w*w0.w;
      s1 += a.x*w1.x + a.y*w1.y + a.z*w1.z + a.w*w1.w;
    }
    #pragma unroll
    for (int msk = 1; msk < 16; msk <<= 1){
      s0 += __shfl_xor(s0, msk);
      s1 += __shfl_xor(s1, msk);
    }
    if (i16 == 0){ imgcL[dm*2] = s0; imgcL[dm*2+1] = s1; }
  }

  // ---- hoisted loop invariants ----
  const int   e0  = i16*4;             // embed dims owned in x_emb phases
  const float wA0 = eW[e0*2],       wB0 = eW[e0*2+1];
  const float wA1 = eW[(e0+1)*2],   wB1 = eW[(e0+1)*2+1];
  const float wA2 = eW[(e0+2)*2],   wB2 = eW[(e0+2)*2+1];
  const float wA3 = eW[(e0+3)*2],   wB3 = eW[(e0+3)*2+1];
  const float be0 = eb[e0], be1 = eb[e0+1], be2 = eb[e0+2], be3 = eb[e0+3];
  const float pb0r = pb[0], pb1r = pb[1];

  // per-lane pred_W slice: rows 0/1, this lane's 8 hidden units
  float pwa[8], pwb[8];
  #pragma unroll
  for (int t = 0; t < 8; t++){
    int ht = wv*16 + hb + (t&3) + 8*(t>>2);
    pwa[t] = pW[ht];
    pwb[t] = pW[2176 + ht];
  }

  // ---- per-lane persistent state: 8 (hidden, sample m) slots ----
  const int thr = 20 - hist[g0 + m];   // mask threshold, one sample/lane
  float c_s[8];
  #pragma unroll
  for (int t = 0; t < 8; t++) c_s[t] = h0[wv*16 + hb + (t&3) + 8*(t>>2)];

  // ---- initial h state into xh[0] (prologue only) ----
  {
    int mm = tid >> 4, j8 = (tid & 15)*8;
    #pragma unroll
    for (int e = 0; e < 8; e++)
      xh[0][mm*200 + 64 + j8 + e] = f2bf(h0[j8 + e]);
  }

  // ---- weight A-fragments (M-side), fp32 -> bf16, register-resident ----
  // tile T row p = lane&31: gate = T*2 + (p>>4), hidden = wv*16 + (p&15)
  bf16x8 Bf[2][12];
  #pragma unroll
  for (int T = 0; T < 2; T++){
    int nrow = (T*2 + (m >> 4))*128 + wv*16 + (m & 15);
    #pragma unroll
    for (int ks = 0; ks < 12; ks++){
      const float* src = (ks < 4) ? (W_ih + nrow*64  + ks*16     + khalf*8)
                                  : (W_hh + nrow*128 + (ks-4)*16 + khalf*8);
      float4 lo = ((const float4*)src)[0];
      float4 hi = ((const float4*)src)[1];
      bf16x8 tf;
      tf[0]=(short)f2bf(lo.x); tf[1]=(short)f2bf(lo.y); tf[2]=(short)f2bf(lo.z); tf[3]=(short)f2bf(lo.w);
      tf[4]=(short)f2bf(hi.x); tf[5]=(short)f2bf(hi.y); tf[6]=(short)f2bf(hi.z); tf[7]=(short)f2bf(hi.w);
      Bf[T][ks] = tf;
    }
  }

  // ---- persistent bias accumulators (2 prologue MFMAs) ----
  f32x16 bias0, bias1;
  {
    f32x16 z;
    #pragma unroll
    for (int e = 0; e < 16; e++) z[e] = 0.f;
    bf16x8 one, bb0, bb1;
    #pragma unroll
    for (int e = 0; e < 8; e++){ one[e] = 0; bb0[e] = 0; bb1[e] = 0; }
    if (khalf == 0){
      one[0] = (short)0x3F80;          // bf16 1.0 at k=0
      int nr0 = ((m >> 4))*128 + wv*16 + (m & 15);
      int nr1 = (2 + (m >> 4))*128 + wv*16 + (m & 15);
      bb0[0] = (short)f2bf(b_ih[nr0] + b_hh[nr0]);
      bb1[0] = (short)f2bf(b_ih[nr1] + b_hh[nr1]);
    }
    bias0 = __builtin_amdgcn_mfma_f32_32x32x16_bf16(bb0, one, z, 0, 0, 0);
    bias1 = __builtin_amdgcn_mfma_f32_32x32x16_bf16(bb1, one, z, 0, 0, 0);
  }

  float pos_r = 0.f;
  if (i16 < 2) pos_r = obs_pos[(size_t)(g0 + dm)*40 + 38 + i16];

  __syncthreads();   // staging (relL, imgcL) visible

  const float imgc0 = imgcL[dm*2], imgc1 = imgcL[dm*2+1];

  // ---- x_emb(t=1) into xh[0] : 4 embed outputs per thread ----
  {
    float2 rr = *((const float2*)&relL[dm*40 + 2]);
    float a0 = fmaxf(0.f, rr.x*wA0 + rr.y*wB0 + be0);
    float a1 = fmaxf(0.f, rr.x*wA1 + rr.y*wB1 + be1);
    float a2 = fmaxf(0.f, rr.x*wA2 + rr.y*wB2 + be2);
    float a3 = fmaxf(0.f, rr.x*wA3 + rr.y*wB3 + be3);
    *((uint2*)&xh[0][dm*200 + e0]) = make_uint2(pk_bf16(a0,a1), pk_bf16(a2,a3));
  }

  const int hofs = m*200 + 64 + wv*16 + hb;   // this lane's h-write base (shorts)
  const unsigned short* xb0 = &xh[0][m*200 + khalf*8];   // B-read bases
  const unsigned short* xb1 = &xh[1][m*200 + khalf*8];
  int b = 0;

  for (int step = 0; step < 49; step++){
    const bool obs = (step < 19);
    __syncthreads();     // barrier1: prev step's writes into xh[b] visible

    const unsigned short* xr = b ? xb1 : xb0;
    f32x16 a0, a1;

    if (obs){
      // ---- full sweep: 12 K-steps, bias as C-in of the first ----
      {
        bf16x8 X[6];
        #pragma unroll
        for (int ks = 0; ks < 6; ks++)
          X[ks] = *((const bf16x8*)&xr[ks*16]);
        a0 = __builtin_amdgcn_mfma_f32_32x32x16_bf16(Bf[0][0], X[0], bias0, 0, 0, 0);
        a1 = __builtin_amdgcn_mfma_f32_32x32x16_bf16(Bf[1][0], X[0], bias1, 0, 0, 0);
        #pragma unroll
        for (int ks = 1; ks < 6; ks++){
          a0 = __builtin_amdgcn_mfma_f32_32x32x16_bf16(Bf[0][ks], X[ks], a0, 0, 0, 0);
          a1 = __builtin_amdgcn_mfma_f32_32x32x16_bf16(Bf[1][ks], X[ks], a1, 0, 0, 0);
        }
      }
      {
        bf16x8 X[6];
        #pragma unroll
        for (int ks = 0; ks < 6; ks++)
          X[ks] = *((const bf16x8*)&xr[(6+ks)*16]);
        #pragma unroll
        for (int ks = 0; ks < 6; ks++){
          a0 = __builtin_amdgcn_mfma_f32_32x32x16_bf16(Bf[0][6+ks], X[ks], a0, 0, 0, 0);
          a1 = __builtin_amdgcn_mfma_f32_32x32x16_bf16(Bf[1][6+ks], X[ks], a1, 0, 0, 0);
        }
      }
      // ---- next step's x_emb (depends only on relL) -> xh[b^1] ----
      if (step < 18){
        int tt = step + 2;             // t+1
        float2 rr = *((const float2*)&relL[dm*40 + tt*2]);
        float x0 = fmaxf(0.f, rr.x*wA0 + rr.y*wB0 + be0);
        float x1 = fmaxf(0.f, rr.x*wA1 + rr.y*wB1 + be1);
        float x2 = fmaxf(0.f, rr.x*wA2 + rr.y*wB2 + be2);
        float x3 = fmaxf(0.f, rr.x*wA3 + rr.y*wB3 + be3);
        *((uint2*)&xh[b^1][dm*200 + e0]) = make_uint2(pk_bf16(x0,x1), pk_bf16(x2,x3));
      }
    } else {
      // ---- PRED: h-frag reads + W_hh MFMAs overlap the (tiny) disp finish ----
      bf16x8 Xh[8];
      #pragma unroll
      for (int ks = 0; ks < 8; ks++)
        Xh[ks] = *((const bf16x8*)&xr[(4+ks)*16]);

      // disp partials precomputed last step: 1 b64 read + 4 shuffles
      float2 pp = pdL[dm][i16];
      float s0 = pp.x, s1 = pp.y;

      a0 = __builtin_amdgcn_mfma_f32_32x32x16_bf16(Bf[0][4], Xh[0], bias0, 0, 0, 0);
      a1 = __builtin_amdgcn_mfma_f32_32x32x16_bf16(Bf[1][4], Xh[0], bias1, 0, 0, 0);
      #pragma unroll
      for (int ks = 1; ks < 8; ks++){
        a0 = __builtin_amdgcn_mfma_f32_32x32x16_bf16(Bf[0][4+ks], Xh[ks], a0, 0, 0, 0);
        a1 = __builtin_amdgcn_mfma_f32_32x32x16_bf16(Bf[1][4+ks], Xh[ks], a1, 0, 0, 0);
      }

      s0 += __shfl_xor(s0, 1);  s1 += __shfl_xor(s1, 1);
      s0 += __shfl_xor(s0, 2);  s1 += __shfl_xor(s1, 2);
      s0 += __shfl_xor(s0, 4);  s1 += __shfl_xor(s1, 4);
      s0 += __shfl_xor(s0, 8);  s1 += __shfl_xor(s1, 8);
      float d0 = s0 + imgc0 + pb0r;
      float d1 = s1 + imgc1 + pb1r;
      if (i16 < 2){
        pos_r += (i16 == 0) ? d0 : d1;
        out[(size_t)(g0 + dm)*60 + (size_t)(step - 19)*2 + i16] = pos_r;
      }
      float x0 = fmaxf(0.f, d0*wA0 + d1*wB0 + be0);
      float x1 = fmaxf(0.f, d0*wA1 + d1*wB1 + be1);
      float x2 = fmaxf(0.f, d0*wA2 + d1*wB2 + be2);
      float x3 = fmaxf(0.f, d0*wA3 + d1*wB3 + be3);
      *((uint2*)&xh[b][dm*200 + e0]) = make_uint2(pk_bf16(x0,x1), pk_bf16(x2,x3));

      __syncthreads();   // barrier2: x_emb visible; only x-part remains
      #pragma unroll
      for (int ks = 0; ks < 4; ks++){
        bf16x8 Xx = *((const bf16x8*)&xr[ks*16]);
        a0 = __builtin_amdgcn_mfma_f32_32x32x16_bf16(Bf[0][ks], Xx, a0, 0, 0, 0);
        a1 = __builtin_amdgcn_mfma_f32_32x32x16_bf16(Bf[1][ks], Xx, a1, 0, 0, 0);
      }
    }

    // ---- lane-local nonlinearity: all 4 gates on this lane ----
    float h2f[8];
    #pragma unroll
    for (int t = 0; t < 8; t++){
      float ig = a0[t];
      float fg = a0[8+t];
      float gg = a1[t];
      float og = a1[8+t];
      float c2 = sigm(fg)*c_s[t] + sigm(ig)*tanh_(gg);
      float h2 = sigm(og)*tanh_(c2);
      if (obs && (step < thr)) c2 = c_s[t];    // c masked-keep
      c_s[t] = c2;
      h2f[t] = h2;
    }

    // ---- h-write: 2 contiguous ds_write_b64 ----
    uint2 Qa = make_uint2(pk_bf16(h2f[0], h2f[1]), pk_bf16(h2f[2], h2f[3]));
    uint2 Qb = make_uint2(pk_bf16(h2f[4], h2f[5]), pk_bf16(h2f[6], h2f[7]));
    if (obs && (step < thr)){
      Qa = *((const uint2*)&xh[b][hofs]);      // old h, bit-exact keep
      Qb = *((const uint2*)&xh[b][hofs + 8]);
    }
    *((uint2*)&xh[b^1][hofs])     = Qa;
    *((uint2*)&xh[b^1][hofs + 8]) = Qb;

    // ---- disp partials for the NEXT (pred) step, from post-mask Q bits ----
    // race-safe: obs->pred separated by barrier1; pred->pred writes occur
    // after barrier2, reads of the next step occur after its barrier1.
    if (step >= 18 && step < 48){
      float v0 = bf2f((unsigned short)(Qa.x & 0xFFFFu));
      float v1 = bf2f((unsigned short)(Qa.x >> 16));
      float v2 = bf2f((unsigned short)(Qa.y & 0xFFFFu));
      float v3 = bf2f((unsigned short)(Qa.y >> 16));
      float v4 = bf2f((unsigned short)(Qb.x & 0xFFFFu));
      float v5 = bf2f((unsigned short)(Qb.x >> 16));
      float v6 = bf2f((unsigned short)(Qb.y & 0xFFFFu));
      float v7 = bf2f((unsigned short)(Qb.y >> 16));
      float pd0 = v0*pwa[0] + v1*pwa[1] + v2*pwa[2] + v3*pwa[3]
                + v4*pwa[4] + v5*pwa[5] + v6*pwa[6] + v7*pwa[7];
      float pd1 = v0*pwb[0] + v1*pwb[1] + v2*pwb[2] + v3*pwb[3]
                + v4*pwb[4] + v5*pwb[5] + v6*pwb[6] + v7*pwb[7];
      pdL[m][wv*2 + khalf] = make_float2(pd0, pd1);
    }

    b ^= 1;
  }
}

extern "C" void kernel_launch(void* const* d_in, const int* in_sizes, int n_in,
                              void* d_out, int out_size, void* d_ws, size_t ws_size,
                              hipStream_t stream){
  const float* img     = (const float*)d_in[0];
  const float* obs_pos = (const float*)d_in[1];
  const int*   hist    = (const int*)d_in[2];
  const float* rel     = (const float*)d_in[3];
  const float* h0      = (const float*)d_in[4];
  const float* W_ih    = (const float*)d_in[5];
  const float* W_hh    = (const float*)d_in[6];
  const float* b_ih    = (const float*)d_in[7];
  const float* b_hh    = (const float*)d_in[8];
  const float* eW      = (const float*)d_in[9];
  const float* eb      = (const float*)d_in[10];
  const float* pW      = (const float*)d_in[11];
  const float* pb      = (const float*)d_in[12];
  float* out = (float*)d_out;
  hipLaunchKernelGGL(traj_kernel, dim3(8192/MBLK), dim3(512), 0, stream,
                     img, obs_pos, hist, rel, h0, W_ih, W_hh, b_ih, b_hh,
                     eW, eb, pW, pb, out);
}

// Round 12
// 253.865 us; speedup vs baseline: 1.0541x; 1.0541x over previous
//
#include <hip/hip_runtime.h>

#define MBLK 32
#define LOG2E 1.4426950408889634f

typedef __attribute__((ext_vector_type(8))) short bf16x8;
typedef __attribute__((ext_vector_type(16))) float f32x16;

__device__ __forceinline__ unsigned short f2bf(float x){
  unsigned int u = __float_as_uint(x);
  u = u + 0x7FFFu + ((u >> 16) & 1u);
  return (unsigned short)(u >> 16);
}
__device__ __forceinline__ float bf2f(unsigned short s){
  return __uint_as_float(((unsigned int)s) << 16);
}
// Pre-scaled nonlinearities: weights/bias for i,f,o gates carry log2e,
// g-gate rows carry 2*log2e -> v_exp_f32 (=2^x) needs no scale mul.
// Negation via free VOP3 input modifier.
__device__ __forceinline__ float sigmS(float x){   // x = log2e * pre-act
  float e; asm("v_exp_f32 %0, -%1" : "=v"(e) : "v"(x));
  return __builtin_amdgcn_rcpf(1.0f + e);
}
__device__ __forceinline__ float tanhS(float x){   // x = 2*log2e * pre-act
  float e; asm("v_exp_f32 %0, %1" : "=v"(e) : "v"(x));
  return 1.0f - 2.0f*__builtin_amdgcn_rcpf(e + 1.0f);
}
// pack 2 f32 -> 2 bf16 (RNE), lo = first operand
__device__ __forceinline__ unsigned int pk_bf16(float lo, float hi){
  unsigned int r;
  asm("v_cvt_pk_bf16_f32 %0, %1, %2" : "=v"(r) : "v"(lo), "v"(hi));
  return r;
}

// 512-thread block, 8 waves, MBLK=32, 256 blocks = 1 block/CU,
// __launch_bounds__(512,2) -> <=256 VGPR, 2 waves/SIMD.
// Gate GEMM via mfma_f32_32x32x16_bf16, WEIGHTS on A(M)-side, ACTIVATIONS
// on B(N)-side: C col=lane&31 = sample; lane-local nonlin; h-write = 2
// contiguous ds_write_b64. (r8 structure, 175us dispatch, passed.)
// vs r10 (which spilled: WRITE 16->33MB from +48 persistent regs):
//  - bias accumulators DROPPED (32 regs) -> r8's Bone/bias-frag MFMA back.
//  - pdL partial-disp KEPT (+16 regs pwa/pwb): pred disp = 1 b64 + 4 shfl;
//    partials computed off-critical-path at step end from post-mask Q bits.
//  - exp2 pre-scaling: log2e folded into i/f/o weight+bias rows,
//    2*log2e into g rows -> sigmS/tanhS use v_exp_f32 directly (-32 VALU
//    mul/step/lane, shorter trans dep chains). Only tanh(c2) keeps a mul.
//  - masked-keep oldQ read hoisted to just after barrier1 (latency
//    hides under MFMA sweep).
__global__ __launch_bounds__(512, 2) void traj_kernel(
    const float* __restrict__ img, const float* __restrict__ obs_pos,
    const int* __restrict__ hist, const float* __restrict__ rel,
    const float* __restrict__ h0, const float* __restrict__ W_ih,
    const float* __restrict__ W_hh, const float* __restrict__ b_ih,
    const float* __restrict__ b_hh, const float* __restrict__ eW,
    const float* __restrict__ eb, const float* __restrict__ pW,
    const float* __restrict__ pb, float* __restrict__ out)
{
  __shared__ unsigned short xh[2][MBLK*200];
  __shared__ float relL[MBLK*40];
  __shared__ float imgcL[MBLK*2];
  __shared__ float2 pdL[32][17];      // disp partials, +1 pad (bank spread)

  const int tid   = threadIdx.x;
  const int wv    = tid >> 6;          // 0..7
  const int lane  = tid & 63;
  const int m     = lane & 31;         // sample owned by this lane (MFMA N-col)
  const int khalf = lane >> 5;         // K-half within a 16-K step
  const int hb    = khalf*4;           // hidden sub-offset
  const int g0    = blockIdx.x * MBLK;
  const int dm    = tid >> 4;          // sample 0..31 (16 threads/sample)
  const int i16   = tid & 15;

  // ---- cooperative staging ----
  for (int idx = tid; idx < MBLK*40; idx += 512) relL[idx] = rel[g0*40 + idx];

  // ---- img_embedding @ pred_W[:,128:].T  (once; constant over pred steps) ----
  {
    const float* row = img + (size_t)(g0 + dm)*2048 + i16*128;
    const float* p0  = pW + 128 + i16*128;
    const float* p1  = pW + 2176 + 128 + i16*128;
    float s0 = 0.f, s1 = 0.f;
    #pragma unroll
    for (int v = 0; v < 32; v++){
      float4 a  = ((const float4*)row)[v];
      float4 w0 = ((const float4*)p0)[v];
      float4 w1 = ((const float4*)p1)[v];
      s0 += a.x*w0.x + a.y*w0.y + a.z*w0.z + a.w*w0.w;
      s1 += a.x*w1.x + a.y*w1.y + a.z*w1.z + a.w*w1.w;
    }
    #pragma unroll
    for (int msk = 1; msk < 16; msk <<= 1){
      s0 += __shfl_xor(s0, msk);
      s1 += __shfl_xor(s1, msk);
    }
    if (i16 == 0){ imgcL[dm*2] = s0; imgcL[dm*2+1] = s1; }
  }

  // ---- hoisted loop invariants ----
  const int   e0  = i16*4;             // embed dims owned in x_emb phases
  const float wA0 = eW[e0*2],       wB0 = eW[e0*2+1];
  const float wA1 = eW[(e0+1)*2],   wB1 = eW[(e0+1)*2+1];
  const float wA2 = eW[(e0+2)*2],   wB2 = eW[(e0+2)*2+1];
  const float wA3 = eW[(e0+3)*2],   wB3 = eW[(e0+3)*2+1];
  const float be0 = eb[e0], be1 = eb[e0+1], be2 = eb[e0+2], be3 = eb[e0+3];
  const float pb0r = pb[0], pb1r = pb[1];

  // per-lane pred_W slice: rows 0/1, this lane's 8 hidden units
  float pwa[8], pwb[8];
  #pragma unroll
  for (int t = 0; t < 8; t++){
    int ht = wv*16 + hb + (t&3) + 8*(t>>2);
    pwa[t] = pW[ht];
    pwb[t] = pW[2176 + ht];
  }

  // ---- per-lane persistent state: 8 (hidden, sample m) slots ----
  const int thr = 20 - hist[g0 + m];   // mask threshold, one sample/lane
  float c_s[8];
  #pragma unroll
  for (int t = 0; t < 8; t++) c_s[t] = h0[wv*16 + hb + (t&3) + 8*(t>>2)];

  // ---- initial h state into xh[0] (prologue only) ----
  {
    int mm = tid >> 4, j8 = (tid & 15)*8;
    #pragma unroll
    for (int e = 0; e < 8; e++)
      xh[0][mm*200 + 64 + j8 + e] = f2bf(h0[j8 + e]);
  }

  // ---- weight A-fragments (M-side), fp32 -> bf16, register-resident ----
  // tile T row p = lane&31: gate = T*2 + (p>>4), hidden = wv*16 + (p&15)
  // exp2 pre-scale: g-gate (==2) rows by 2*log2e, others by log2e.
  bf16x8 Bf[2][13];
  #pragma unroll
  for (int T = 0; T < 2; T++){
    int gate = T*2 + (m >> 4);
    int nrow = gate*128 + wv*16 + (m & 15);
    const float wsc = (gate == 2) ? 2.0f*LOG2E : LOG2E;
    #pragma unroll
    for (int ks = 0; ks < 12; ks++){
      const float* src = (ks < 4) ? (W_ih + nrow*64  + ks*16     + khalf*8)
                                  : (W_hh + nrow*128 + (ks-4)*16 + khalf*8);
      float4 lo = ((const float4*)src)[0];
      float4 hi = ((const float4*)src)[1];
      bf16x8 tf;
      tf[0]=(short)f2bf(lo.x*wsc); tf[1]=(short)f2bf(lo.y*wsc);
      tf[2]=(short)f2bf(lo.z*wsc); tf[3]=(short)f2bf(lo.w*wsc);
      tf[4]=(short)f2bf(hi.x*wsc); tf[5]=(short)f2bf(hi.y*wsc);
      tf[6]=(short)f2bf(hi.z*wsc); tf[7]=(short)f2bf(hi.w*wsc);
      Bf[T][ks] = tf;
    }
    // ks 12: bias column (k=192 exactly -> khalf 0, elem 0)
    bf16x8 bb;
    #pragma unroll
    for (int e = 0; e < 8; e++) bb[e] = 0;
    if (khalf == 0) bb[0] = (short)f2bf((b_ih[nrow] + b_hh[nrow])*wsc);
    Bf[T][12] = bb;
  }
  // B-side const-1 column for the bias K-step
  bf16x8 Bone;
  #pragma unroll
  for (int e = 0; e < 8; e++) Bone[e] = 0;
  if (khalf == 0) Bone[0] = (short)0x3F80;   // bf16 1.0

  float pos_r = 0.f;
  if (i16 < 2) pos_r = obs_pos[(size_t)(g0 + dm)*40 + 38 + i16];

  __syncthreads();   // staging (relL, imgcL) visible

  const float imgc0 = imgcL[dm*2], imgc1 = imgcL[dm*2+1];

  // ---- x_emb(t=1) into xh[0] : 4 embed outputs per thread ----
  {
    float2 rr = *((const float2*)&relL[dm*40 + 2]);
    float a0 = fmaxf(0.f, rr.x*wA0 + rr.y*wB0 + be0);
    float a1 = fmaxf(0.f, rr.x*wA1 + rr.y*wB1 + be1);
    float a2 = fmaxf(0.f, rr.x*wA2 + rr.y*wB2 + be2);
    float a3 = fmaxf(0.f, rr.x*wA3 + rr.y*wB3 + be3);
    *((uint2*)&xh[0][dm*200 + e0]) = make_uint2(pk_bf16(a0,a1), pk_bf16(a2,a3));
  }

  const int hofs = m*200 + 64 + wv*16 + hb;   // this lane's h-write base (shorts)
  const unsigned short* xb0 = &xh[0][m*200 + khalf*8];   // B-read bases
  const unsigned short* xb1 = &xh[1][m*200 + khalf*8];
  int b = 0;

  for (int step = 0; step < 49; step++){
    const bool obs = (step < 19);
    __syncthreads();     // barrier1: prev step's writes into xh[b] visible

    const unsigned short* xr = b ? xb1 : xb0;
    f32x16 a0, a1;
    #pragma unroll
    for (int e = 0; e < 16; e++){ a0[e] = 0.f; a1[e] = 0.f; }

    uint2 QaOld, QbOld;   // masked-keep source, hoisted early (obs only)

    if (obs){
      // early oldQ read: latency hides under the MFMA sweep
      QaOld = *((const uint2*)&xh[b][hofs]);
      QbOld = *((const uint2*)&xh[b][hofs + 8]);
      // ---- full sweep: bias step + 12 activation K-steps (2x6) ----
      a0 = __builtin_amdgcn_mfma_f32_32x32x16_bf16(Bf[0][12], Bone, a0, 0, 0, 0);
      a1 = __builtin_amdgcn_mfma_f32_32x32x16_bf16(Bf[1][12], Bone, a1, 0, 0, 0);
      {
        bf16x8 X[6];
        #pragma unroll
        for (int ks = 0; ks < 6; ks++)
          X[ks] = *((const bf16x8*)&xr[ks*16]);
        #pragma unroll
        for (int ks = 0; ks < 6; ks++){
          a0 = __builtin_amdgcn_mfma_f32_32x32x16_bf16(Bf[0][ks], X[ks], a0, 0, 0, 0);
          a1 = __builtin_amdgcn_mfma_f32_32x32x16_bf16(Bf[1][ks], X[ks], a1, 0, 0, 0);
        }
      }
      {
        bf16x8 X[6];
        #pragma unroll
        for (int ks = 0; ks < 6; ks++)
          X[ks] = *((const bf16x8*)&xr[(6+ks)*16]);
        #pragma unroll
        for (int ks = 0; ks < 6; ks++){
          a0 = __builtin_amdgcn_mfma_f32_32x32x16_bf16(Bf[0][6+ks], X[ks], a0, 0, 0, 0);
          a1 = __builtin_amdgcn_mfma_f32_32x32x16_bf16(Bf[1][6+ks], X[ks], a1, 0, 0, 0);
        }
      }
      // ---- next step's x_emb (depends only on relL) -> xh[b^1] ----
      if (step < 18){
        int tt = step + 2;             // t+1
        float2 rr = *((const float2*)&relL[dm*40 + tt*2]);
        float x0 = fmaxf(0.f, rr.x*wA0 + rr.y*wB0 + be0);
        float x1 = fmaxf(0.f, rr.x*wA1 + rr.y*wB1 + be1);
        float x2 = fmaxf(0.f, rr.x*wA2 + rr.y*wB2 + be2);
        float x3 = fmaxf(0.f, rr.x*wA3 + rr.y*wB3 + be3);
        *((uint2*)&xh[b^1][dm*200 + e0]) = make_uint2(pk_bf16(x0,x1), pk_bf16(x2,x3));
      }
    } else {
      // ---- PRED: h-frag reads + W_hh/bias MFMAs overlap the disp finish ----
      bf16x8 Xh[8];
      #pragma unroll
      for (int ks = 0; ks < 8; ks++)
        Xh[ks] = *((const bf16x8*)&xr[(4+ks)*16]);

      // disp partials precomputed last step: 1 b64 read + 4 shuffles
      float2 pp = pdL[dm][i16];
      float s0 = pp.x, s1 = pp.y;

      a0 = __builtin_amdgcn_mfma_f32_32x32x16_bf16(Bf[0][12], Bone, a0, 0, 0, 0);
      a1 = __builtin_amdgcn_mfma_f32_32x32x16_bf16(Bf[1][12], Bone, a1, 0, 0, 0);
      #pragma unroll
      for (int ks = 0; ks < 8; ks++){
        a0 = __builtin_amdgcn_mfma_f32_32x32x16_bf16(Bf[0][4+ks], Xh[ks], a0, 0, 0, 0);
        a1 = __builtin_amdgcn_mfma_f32_32x32x16_bf16(Bf[1][4+ks], Xh[ks], a1, 0, 0, 0);
      }

      s0 += __shfl_xor(s0, 1);  s1 += __shfl_xor(s1, 1);
      s0 += __shfl_xor(s0, 2);  s1 += __shfl_xor(s1, 2);
      s0 += __shfl_xor(s0, 4);  s1 += __shfl_xor(s1, 4);
      s0 += __shfl_xor(s0, 8);  s1 += __shfl_xor(s1, 8);
      float d0 = s0 + imgc0 + pb0r;
      float d1 = s1 + imgc1 + pb1r;
      if (i16 < 2){
        pos_r += (i16 == 0) ? d0 : d1;
        out[(size_t)(g0 + dm)*60 + (size_t)(step - 19)*2 + i16] = pos_r;
      }
      float x0 = fmaxf(0.f, d0*wA0 + d1*wB0 + be0);
      float x1 = fmaxf(0.f, d0*wA1 + d1*wB1 + be1);
      float x2 = fmaxf(0.f, d0*wA2 + d1*wB2 + be2);
      float x3 = fmaxf(0.f, d0*wA3 + d1*wB3 + be3);
      *((uint2*)&xh[b][dm*200 + e0]) = make_uint2(pk_bf16(x0,x1), pk_bf16(x2,x3));

      __syncthreads();   // barrier2: x_emb visible; only x-part remains
      #pragma unroll
      for (int ks = 0; ks < 4; ks++){
        bf16x8 Xx = *((const bf16x8*)&xr[ks*16]);
        a0 = __builtin_amdgcn_mfma_f32_32x32x16_bf16(Bf[0][ks], Xx, a0, 0, 0, 0);
        a1 = __builtin_amdgcn_mfma_f32_32x32x16_bf16(Bf[1][ks], Xx, a1, 0, 0, 0);
      }
    }

    // ---- lane-local nonlinearity (pre-scaled exp2 forms) ----
    float h2f[8];
    #pragma unroll
    for (int t = 0; t < 8; t++){
      float ig = a0[t];
      float fg = a0[8+t];
      float gg = a1[t];
      float og = a1[8+t];
      float c2 = sigmS(fg)*c_s[t] + sigmS(ig)*tanhS(gg);
      float h2 = sigmS(og)*tanhS(c2*(2.0f*LOG2E));
      if (obs && (step < thr)) c2 = c_s[t];    // c masked-keep
      c_s[t] = c2;
      h2f[t] = h2;
    }

    // ---- h-write: 2 contiguous ds_write_b64 ----
    uint2 Qa = make_uint2(pk_bf16(h2f[0], h2f[1]), pk_bf16(h2f[2], h2f[3]));
    uint2 Qb = make_uint2(pk_bf16(h2f[4], h2f[5]), pk_bf16(h2f[6], h2f[7]));
    if (obs && (step < thr)){
      Qa = QaOld;                      // old h, bit-exact keep (hoisted read)
      Qb = QbOld;
    }
    *((uint2*)&xh[b^1][hofs])     = Qa;
    *((uint2*)&xh[b^1][hofs + 8]) = Qb;

    // ---- disp partials for the NEXT (pred) step, from post-mask Q bits ----
    // race-safe: obs->pred separated by barrier1; pred->pred writes occur
    // after barrier2, reads of the next step occur after its barrier1.
    if (step >= 18 && step < 48){
      float v0 = bf2f((unsigned short)(Qa.x & 0xFFFFu));
      float v1 = bf2f((unsigned short)(Qa.x >> 16));
      float v2 = bf2f((unsigned short)(Qa.y & 0xFFFFu));
      float v3 = bf2f((unsigned short)(Qa.y >> 16));
      float v4 = bf2f((unsigned short)(Qb.x & 0xFFFFu));
      float v5 = bf2f((unsigned short)(Qb.x >> 16));
      float v6 = bf2f((unsigned short)(Qb.y & 0xFFFFu));
      float v7 = bf2f((unsigned short)(Qb.y >> 16));
      float pd0 = v0*pwa[0] + v1*pwa[1] + v2*pwa[2] + v3*pwa[3]
                + v4*pwa[4] + v5*pwa[5] + v6*pwa[6] + v7*pwa[7];
      float pd1 = v0*pwb[0] + v1*pwb[1] + v2*pwb[2] + v3*pwb[3]
                + v4*pwb[4] + v5*pwb[5] + v6*pwb[6] + v7*pwb[7];
      pdL[m][wv*2 + khalf] = make_float2(pd0, pd1);
    }

    b ^= 1;
  }
}

extern "C" void kernel_launch(void* const* d_in, const int* in_sizes, int n_in,
                              void* d_out, int out_size, void* d_ws, size_t ws_size,
                              hipStream_t stream){
  const float* img     = (const float*)d_in[0];
  const float* obs_pos = (const float*)d_in[1];
  const int*   hist    = (const int*)d_in[2];
  const float* rel     = (const float*)d_in[3];
  const float* h0      = (const float*)d_in[4];
  const float* W_ih    = (const float*)d_in[5];
  const float* W_hh    = (const float*)d_in[6];
  const float* b_ih    = (const float*)d_in[7];
  const float* b_hh    = (const float*)d_in[8];
  const float* eW      = (const float*)d_in[9];
  const float* eb      = (const float*)d_in[10];
  const float* pW      = (const float*)d_in[11];
  const float* pb      = (const float*)d_in[12];
  float* out = (float*)d_out;
  hipLaunchKernelGGL(traj_kernel, dim3(8192/MBLK), dim3(512), 0, stream,
                     img, obs_pos, hist, rel, h0, W_ih, W_hh, b_ih, b_hh,
                     eW, eb, pW, pb, out);
}

// Round 13
// 250.571 us; speedup vs baseline: 1.0679x; 1.0131x over previous
//
#include <hip/hip_runtime.h>

#define MBLK 32
#define LOG2E 1.4426950408889634f

typedef __attribute__((ext_vector_type(8))) short bf16x8;
typedef __attribute__((ext_vector_type(16))) float f32x16;

__device__ __forceinline__ unsigned short f2bf(float x){
  unsigned int u = __float_as_uint(x);
  u = u + 0x7FFFu + ((u >> 16) & 1u);
  return (unsigned short)(u >> 16);
}
__device__ __forceinline__ float bf2f(unsigned short s){
  return __uint_as_float(((unsigned int)s) << 16);
}
// pack 2 f32 -> 2 bf16 (RNE), lo = first operand
__device__ __forceinline__ unsigned int pk_bf16(float lo, float hi){
  unsigned int r;
  asm("v_cvt_pk_bf16_f32 %0, %1, %2" : "=v"(r) : "v"(lo), "v"(hi));
  return r;
}

// 512-thread block, 8 waves, MBLK=32, 256 blocks = 1 block/CU,
// __launch_bounds__(512,2) -> <=256 VGPR, 2 waves/SIMD.
// Gate GEMM via mfma_f32_32x32x16_bf16, WEIGHTS on A(M)-side, ACTIVATIONS
// on B(N)-side: C col=lane&31 = sample; lane-local nonlin; h-write = 2
// contiguous ds_write_b64. exp2 pre-scaling: i/f/o rows carry log2e,
// g rows carry 2*log2e (weights AND bias).
// vs r12 (172.2us dispatch, passed) -- single-theme trans cut:
//  - fused-denominator c-update: c2' = [c'*B*C + K2*A*D]*rcp(A*B*C),
//    A=1+Ef B=1+Ei C=Eg+1 D=Eg-1 -> ONE rcp replaces three (sigm f, sigm
//    i, tanh g). Data-bounded safe (|preact|<=~8 -> Eg<=2^22).
//  - c state kept in 2log2e-scaled domain (c' = K2*c) -> Ec = exp2(c2')
//    directly, no per-slot scale mul. h2 keeps the GRACEFUL tanh form
//    (1-2*rcp(Ec+1) -> 1 at Ec=inf; same exposure r12 passed with).
//  - per slot: 5 exp + 3 rcp (was 5+5); -16 trans instr/lane/step.
// Everything else identical to r12 (pdL partial-disp, oldQ hoist, pred
// 2-barrier split, x_emb lookahead).
__global__ __launch_bounds__(512, 2) void traj_kernel(
    const float* __restrict__ img, const float* __restrict__ obs_pos,
    const int* __restrict__ hist, const float* __restrict__ rel,
    const float* __restrict__ h0, const float* __restrict__ W_ih,
    const float* __restrict__ W_hh, const float* __restrict__ b_ih,
    const float* __restrict__ b_hh, const float* __restrict__ eW,
    const float* __restrict__ eb, const float* __restrict__ pW,
    const float* __restrict__ pb, float* __restrict__ out)
{
  __shared__ unsigned short xh[2][MBLK*200];
  __shared__ float relL[MBLK*40];
  __shared__ float imgcL[MBLK*2];
  __shared__ float2 pdL[32][17];      // disp partials, +1 pad (bank spread)

  const int tid   = threadIdx.x;
  const int wv    = tid >> 6;          // 0..7
  const int lane  = tid & 63;
  const int m     = lane & 31;         // sample owned by this lane (MFMA N-col)
  const int khalf = lane >> 5;         // K-half within a 16-K step
  const int hb    = khalf*4;           // hidden sub-offset
  const int g0    = blockIdx.x * MBLK;
  const int dm    = tid >> 4;          // sample 0..31 (16 threads/sample)
  const int i16   = tid & 15;

  // ---- cooperative staging ----
  for (int idx = tid; idx < MBLK*40; idx += 512) relL[idx] = rel[g0*40 + idx];

  // ---- img_embedding @ pred_W[:,128:].T  (once; constant over pred steps) ----
  {
    const float* row = img + (size_t)(g0 + dm)*2048 + i16*128;
    const float* p0  = pW + 128 + i16*128;
    const float* p1  = pW + 2176 + 128 + i16*128;
    float s0 = 0.f, s1 = 0.f;
    #pragma unroll
    for (int v = 0; v < 32; v++){
      float4 a  = ((const float4*)row)[v];
      float4 w0 = ((const float4*)p0)[v];
      float4 w1 = ((const float4*)p1)[v];
      s0 += a.x*w0.x + a.y*w0.y + a.z*w0.z + a.w*w0.w;
      s1 += a.x*w1.x + a.y*w1.y + a.z*w1.z + a.w*w1.w;
    }
    #pragma unroll
    for (int msk = 1; msk < 16; msk <<= 1){
      s0 += __shfl_xor(s0, msk);
      s1 += __shfl_xor(s1, msk);
    }
    if (i16 == 0){ imgcL[dm*2] = s0; imgcL[dm*2+1] = s1; }
  }

  // ---- hoisted loop invariants ----
  const int   e0  = i16*4;             // embed dims owned in x_emb phases
  const float wA0 = eW[e0*2],       wB0 = eW[e0*2+1];
  const float wA1 = eW[(e0+1)*2],   wB1 = eW[(e0+1)*2+1];
  const float wA2 = eW[(e0+2)*2],   wB2 = eW[(e0+2)*2+1];
  const float wA3 = eW[(e0+3)*2],   wB3 = eW[(e0+3)*2+1];
  const float be0 = eb[e0], be1 = eb[e0+1], be2 = eb[e0+2], be3 = eb[e0+3];
  const float pb0r = pb[0], pb1r = pb[1];
  const float K2  = 2.0f*LOG2E;

  // per-lane pred_W slice: rows 0/1, this lane's 8 hidden units
  float pwa[8], pwb[8];
  #pragma unroll
  for (int t = 0; t < 8; t++){
    int ht = wv*16 + hb + (t&3) + 8*(t>>2);
    pwa[t] = pW[ht];
    pwb[t] = pW[2176 + ht];
  }

  // ---- per-lane persistent state: 8 (hidden, sample m) slots ----
  // c stored PRE-SCALED: c' = 2*log2e * c
  const int thr = 20 - hist[g0 + m];   // mask threshold, one sample/lane
  float c_s[8];
  #pragma unroll
  for (int t = 0; t < 8; t++) c_s[t] = K2*h0[wv*16 + hb + (t&3) + 8*(t>>2)];

  // ---- initial h state into xh[0] (prologue only) ----
  {
    int mm = tid >> 4, j8 = (tid & 15)*8;
    #pragma unroll
    for (int e = 0; e < 8; e++)
      xh[0][mm*200 + 64 + j8 + e] = f2bf(h0[j8 + e]);
  }

  // ---- weight A-fragments (M-side), fp32 -> bf16, register-resident ----
  // tile T row p = lane&31: gate = T*2 + (p>>4), hidden = wv*16 + (p&15)
  // exp2 pre-scale: g-gate (==2) rows by 2*log2e, others by log2e.
  bf16x8 Bf[2][13];
  #pragma unroll
  for (int T = 0; T < 2; T++){
    int gate = T*2 + (m >> 4);
    int nrow = gate*128 + wv*16 + (m & 15);
    const float wsc = (gate == 2) ? 2.0f*LOG2E : LOG2E;
    #pragma unroll
    for (int ks = 0; ks < 12; ks++){
      const float* src = (ks < 4) ? (W_ih + nrow*64  + ks*16     + khalf*8)
                                  : (W_hh + nrow*128 + (ks-4)*16 + khalf*8);
      float4 lo = ((const float4*)src)[0];
      float4 hi = ((const float4*)src)[1];
      bf16x8 tf;
      tf[0]=(short)f2bf(lo.x*wsc); tf[1]=(short)f2bf(lo.y*wsc);
      tf[2]=(short)f2bf(lo.z*wsc); tf[3]=(short)f2bf(lo.w*wsc);
      tf[4]=(short)f2bf(hi.x*wsc); tf[5]=(short)f2bf(hi.y*wsc);
      tf[6]=(short)f2bf(hi.z*wsc); tf[7]=(short)f2bf(hi.w*wsc);
      Bf[T][ks] = tf;
    }
    // ks 12: bias column (k=192 exactly -> khalf 0, elem 0)
    bf16x8 bb;
    #pragma unroll
    for (int e = 0; e < 8; e++) bb[e] = 0;
    if (khalf == 0) bb[0] = (short)f2bf((b_ih[nrow] + b_hh[nrow])*wsc);
    Bf[T][12] = bb;
  }
  // B-side const-1 column for the bias K-step
  bf16x8 Bone;
  #pragma unroll
  for (int e = 0; e < 8; e++) Bone[e] = 0;
  if (khalf == 0) Bone[0] = (short)0x3F80;   // bf16 1.0

  float pos_r = 0.f;
  if (i16 < 2) pos_r = obs_pos[(size_t)(g0 + dm)*40 + 38 + i16];

  __syncthreads();   // staging (relL, imgcL) visible

  const float imgc0 = imgcL[dm*2], imgc1 = imgcL[dm*2+1];

  // ---- x_emb(t=1) into xh[0] : 4 embed outputs per thread ----
  {
    float2 rr = *((const float2*)&relL[dm*40 + 2]);
    float a0 = fmaxf(0.f, rr.x*wA0 + rr.y*wB0 + be0);
    float a1 = fmaxf(0.f, rr.x*wA1 + rr.y*wB1 + be1);
    float a2 = fmaxf(0.f, rr.x*wA2 + rr.y*wB2 + be2);
    float a3 = fmaxf(0.f, rr.x*wA3 + rr.y*wB3 + be3);
    *((uint2*)&xh[0][dm*200 + e0]) = make_uint2(pk_bf16(a0,a1), pk_bf16(a2,a3));
  }

  const int hofs = m*200 + 64 + wv*16 + hb;   // this lane's h-write base (shorts)
  const unsigned short* xb0 = &xh[0][m*200 + khalf*8];   // B-read bases
  const unsigned short* xb1 = &xh[1][m*200 + khalf*8];
  int b = 0;

  for (int step = 0; step < 49; step++){
    const bool obs = (step < 19);
    __syncthreads();     // barrier1: prev step's writes into xh[b] visible

    const unsigned short* xr = b ? xb1 : xb0;
    f32x16 a0, a1;
    #pragma unroll
    for (int e = 0; e < 16; e++){ a0[e] = 0.f; a1[e] = 0.f; }

    uint2 QaOld, QbOld;   // masked-keep source, hoisted early (obs only)

    if (obs){
      // early oldQ read: latency hides under the MFMA sweep
      QaOld = *((const uint2*)&xh[b][hofs]);
      QbOld = *((const uint2*)&xh[b][hofs + 8]);
      // ---- full sweep: bias step + 12 activation K-steps (2x6) ----
      a0 = __builtin_amdgcn_mfma_f32_32x32x16_bf16(Bf[0][12], Bone, a0, 0, 0, 0);
      a1 = __builtin_amdgcn_mfma_f32_32x32x16_bf16(Bf[1][12], Bone, a1, 0, 0, 0);
      {
        bf16x8 X[6];
        #pragma unroll
        for (int ks = 0; ks < 6; ks++)
          X[ks] = *((const bf16x8*)&xr[ks*16]);
        #pragma unroll
        for (int ks = 0; ks < 6; ks++){
          a0 = __builtin_amdgcn_mfma_f32_32x32x16_bf16(Bf[0][ks], X[ks], a0, 0, 0, 0);
          a1 = __builtin_amdgcn_mfma_f32_32x32x16_bf16(Bf[1][ks], X[ks], a1, 0, 0, 0);
        }
      }
      {
        bf16x8 X[6];
        #pragma unroll
        for (int ks = 0; ks < 6; ks++)
          X[ks] = *((const bf16x8*)&xr[(6+ks)*16]);
        #pragma unroll
        for (int ks = 0; ks < 6; ks++){
          a0 = __builtin_amdgcn_mfma_f32_32x32x16_bf16(Bf[0][6+ks], X[ks], a0, 0, 0, 0);
          a1 = __builtin_amdgcn_mfma_f32_32x32x16_bf16(Bf[1][6+ks], X[ks], a1, 0, 0, 0);
        }
      }
      // ---- next step's x_emb (depends only on relL) -> xh[b^1] ----
      if (step < 18){
        int tt = step + 2;             // t+1
        float2 rr = *((const float2*)&relL[dm*40 + tt*2]);
        float x0 = fmaxf(0.f, rr.x*wA0 + rr.y*wB0 + be0);
        float x1 = fmaxf(0.f, rr.x*wA1 + rr.y*wB1 + be1);
        float x2 = fmaxf(0.f, rr.x*wA2 + rr.y*wB2 + be2);
        float x3 = fmaxf(0.f, rr.x*wA3 + rr.y*wB3 + be3);
        *((uint2*)&xh[b^1][dm*200 + e0]) = make_uint2(pk_bf16(x0,x1), pk_bf16(x2,x3));
      }
    } else {
      // ---- PRED: h-frag reads + W_hh/bias MFMAs overlap the disp finish ----
      bf16x8 Xh[8];
      #pragma unroll
      for (int ks = 0; ks < 8; ks++)
        Xh[ks] = *((const bf16x8*)&xr[(4+ks)*16]);

      // disp partials precomputed last step: 1 b64 read + 4 shuffles
      float2 pp = pdL[dm][i16];
      float s0 = pp.x, s1 = pp.y;

      a0 = __builtin_amdgcn_mfma_f32_32x32x16_bf16(Bf[0][12], Bone, a0, 0, 0, 0);
      a1 = __builtin_amdgcn_mfma_f32_32x32x16_bf16(Bf[1][12], Bone, a1, 0, 0, 0);
      #pragma unroll
      for (int ks = 0; ks < 8; ks++){
        a0 = __builtin_amdgcn_mfma_f32_32x32x16_bf16(Bf[0][4+ks], Xh[ks], a0, 0, 0, 0);
        a1 = __builtin_amdgcn_mfma_f32_32x32x16_bf16(Bf[1][4+ks], Xh[ks], a1, 0, 0, 0);
      }

      s0 += __shfl_xor(s0, 1);  s1 += __shfl_xor(s1, 1);
      s0 += __shfl_xor(s0, 2);  s1 += __shfl_xor(s1, 2);
      s0 += __shfl_xor(s0, 4);  s1 += __shfl_xor(s1, 4);
      s0 += __shfl_xor(s0, 8);  s1 += __shfl_xor(s1, 8);
      float d0 = s0 + imgc0 + pb0r;
      float d1 = s1 + imgc1 + pb1r;
      if (i16 < 2){
        pos_r += (i16 == 0) ? d0 : d1;
        out[(size_t)(g0 + dm)*60 + (size_t)(step - 19)*2 + i16] = pos_r;
      }
      float x0 = fmaxf(0.f, d0*wA0 + d1*wB0 + be0);
      float x1 = fmaxf(0.f, d0*wA1 + d1*wB1 + be1);
      float x2 = fmaxf(0.f, d0*wA2 + d1*wB2 + be2);
      float x3 = fmaxf(0.f, d0*wA3 + d1*wB3 + be3);
      *((uint2*)&xh[b][dm*200 + e0]) = make_uint2(pk_bf16(x0,x1), pk_bf16(x2,x3));

      __syncthreads();   // barrier2: x_emb visible; only x-part remains
      #pragma unroll
      for (int ks = 0; ks < 4; ks++){
        bf16x8 Xx = *((const bf16x8*)&xr[ks*16]);
        a0 = __builtin_amdgcn_mfma_f32_32x32x16_bf16(Bf[0][ks], Xx, a0, 0, 0, 0);
        a1 = __builtin_amdgcn_mfma_f32_32x32x16_bf16(Bf[1][ks], Xx, a1, 0, 0, 0);
      }
    }

    // ---- lane-local nonlinearity: fused-denominator c-update ----
    // a0[t]=i', a0[8+t]=f', a1[8+t]=o' (log2e-scaled); a1[t]=g' (2log2e).
    // c2' = [c'*B*C + K2*A*D] / (A*B*C);  A=1+Ef B=1+Ei C=Eg+1 D=Eg-1
    float h2f[8];
    #pragma unroll
    for (int t = 0; t < 8; t++){
      float ip = a0[t];
      float fp = a0[8+t];
      float gp = a1[t];
      float op = a1[8+t];
      float Ef; asm("v_exp_f32 %0, -%1" : "=v"(Ef) : "v"(fp));
      float Ei; asm("v_exp_f32 %0, -%1" : "=v"(Ei) : "v"(ip));
      float Eg; asm("v_exp_f32 %0, %1"  : "=v"(Eg) : "v"(gp));
      float A = 1.0f + Ef;
      float B = 1.0f + Ei;
      float C = Eg + 1.0f;
      float D = Eg - 1.0f;
      float t1 = c_s[t]*B;
      float numer = fmaf(t1, C, (K2*A)*D);
      float denom = (A*B)*C;
      float c2p = numer*__builtin_amdgcn_rcpf(denom);   // c' (pre-scaled)
      // h2 = sigm(o)*tanh(c2); graceful at Ec=inf (tanh->1)
      float Eo; asm("v_exp_f32 %0, -%1" : "=v"(Eo) : "v"(op));
      float Ec; asm("v_exp_f32 %0, %1"  : "=v"(Ec) : "v"(c2p));
      float so = __builtin_amdgcn_rcpf(1.0f + Eo);
      float th = 1.0f - 2.0f*__builtin_amdgcn_rcpf(Ec + 1.0f);
      float h2 = so*th;
      if (obs && (step < thr)) c2p = c_s[t];   // c masked-keep (scaled dom.)
      c_s[t] = c2p;
      h2f[t] = h2;
    }

    // ---- h-write: 2 contiguous ds_write_b64 ----
    uint2 Qa = make_uint2(pk_bf16(h2f[0], h2f[1]), pk_bf16(h2f[2], h2f[3]));
    uint2 Qb = make_uint2(pk_bf16(h2f[4], h2f[5]), pk_bf16(h2f[6], h2f[7]));
    if (obs && (step < thr)){
      Qa = QaOld;                      // old h, bit-exact keep (hoisted read)
      Qb = QbOld;
    }
    *((uint2*)&xh[b^1][hofs])     = Qa;
    *((uint2*)&xh[b^1][hofs + 8]) = Qb;

    // ---- disp partials for the NEXT (pred) step, from post-mask Q bits ----
    // race-safe: obs->pred separated by barrier1; pred->pred writes occur
    // after barrier2, reads of the next step occur after its barrier1.
    if (step >= 18 && step < 48){
      float v0 = bf2f((unsigned short)(Qa.x & 0xFFFFu));
      float v1 = bf2f((unsigned short)(Qa.x >> 16));
      float v2 = bf2f((unsigned short)(Qa.y & 0xFFFFu));
      float v3 = bf2f((unsigned short)(Qa.y >> 16));
      float v4 = bf2f((unsigned short)(Qb.x & 0xFFFFu));
      float v5 = bf2f((unsigned short)(Qb.x >> 16));
      float v6 = bf2f((unsigned short)(Qb.y & 0xFFFFu));
      float v7 = bf2f((unsigned short)(Qb.y >> 16));
      float pd0 = v0*pwa[0] + v1*pwa[1] + v2*pwa[2] + v3*pwa[3]
                + v4*pwa[4] + v5*pwa[5] + v6*pwa[6] + v7*pwa[7];
      float pd1 = v0*pwb[0] + v1*pwb[1] + v2*pwb[2] + v3*pwb[3]
                + v4*pwb[4] + v5*pwb[5] + v6*pwb[6] + v7*pwb[7];
      pdL[m][wv*2 + khalf] = make_float2(pd0, pd1);
    }

    b ^= 1;
  }
}

extern "C" void kernel_launch(void* const* d_in, const int* in_sizes, int n_in,
                              void* d_out, int out_size, void* d_ws, size_t ws_size,
                              hipStream_t stream){
  const float* img     = (const float*)d_in[0];
  const float* obs_pos = (const float*)d_in[1];
  const int*   hist    = (const int*)d_in[2];
  const float* rel     = (const float*)d_in[3];
  const float* h0      = (const float*)d_in[4];
  const float* W_ih    = (const float*)d_in[5];
  const float* W_hh    = (const float*)d_in[6];
  const float* b_ih    = (const float*)d_in[7];
  const float* b_hh    = (const float*)d_in[8];
  const float* eW      = (const float*)d_in[9];
  const float* eb      = (const float*)d_in[10];
  const float* pW      = (const float*)d_in[11];
  const float* pb      = (const float*)d_in[12];
  float* out = (float*)d_out;
  hipLaunchKernelGGL(traj_kernel, dim3(8192/MBLK), dim3(512), 0, stream,
                     img, obs_pos, hist, rel, h0, W_ih, W_hh, b_ih, b_hh,
                     eW, eb, pW, pb, out);
}